// Round 12
// baseline (47.516 us; speedup 1.0000x reference)
//
#include <hip/hip_runtime.h>
#include <math.h>

#define I_N 96
#define C_N 96
#define R_N 36
#define W_N 48
#define D_N 256
#define NIMG 4
#define NCOL (NIMG * R_N)   // 144
#define LAM_SM 9.0f
#define LAM_LSE 6.0f
#define MARGIN_F 0.2f
#define AWS 56              // e-matrix LDS row stride (shorts): 112B

#define IMG_ELEMS (I_N * R_N * D_N)   // 884736 = 24 tiles * 72 frags * 512
#define REC_ELEMS (C_N * W_N * D_N)   // 1179648

// workspace layout
#define WSF_SCORES 0          // 9216 floats
#define WSF_N1     9216       // 3456 floats
#define WSF_SHBASE 12800      // shorts begin here
#define SH_IMG 0
#define SH_REC IMG_ELEMS
#define SH_GP  (IMG_ELEMS + REC_ELEMS)   // 96*6*512 shorts

typedef __attribute__((ext_vector_type(8))) short short8;
typedef __attribute__((ext_vector_type(4))) float f32x4;

#define MFMA16(a, b, c) __builtin_amdgcn_mfma_f32_16x16x32_bf16(a, b, c, 0, 0, 0)

__device__ __forceinline__ unsigned short f32_to_bf16(float f) {
    unsigned int u = __float_as_uint(f);
    return (unsigned short)((u + 0x7fffu + ((u >> 16) & 1u)) >> 16);
}
__device__ __forceinline__ float dot4f(float4 a, float4 b) {
    return a.x * b.x + a.y * b.y + a.z * b.z + a.w * b.w;
}
__device__ __forceinline__ uint4 cvt8u(float4 v0, float4 v1) {
    uint4 o;
    o.x = (unsigned)f32_to_bf16(v0.x) | ((unsigned)f32_to_bf16(v0.y) << 16);
    o.y = (unsigned)f32_to_bf16(v0.z) | ((unsigned)f32_to_bf16(v0.w) << 16);
    o.z = (unsigned)f32_to_bf16(v1.x) | ((unsigned)f32_to_bf16(v1.y) << 16);
    o.w = (unsigned)f32_to_bf16(v1.z) | ((unsigned)f32_to_bf16(v1.w) << 16);
    return o;
}
__device__ __forceinline__ short8 cvt8s(float4 v0, float4 v1) {
    short8 s;
    s[0] = (short)f32_to_bf16(v0.x); s[1] = (short)f32_to_bf16(v0.y);
    s[2] = (short)f32_to_bf16(v0.z); s[3] = (short)f32_to_bf16(v0.w);
    s[4] = (short)f32_to_bf16(v1.x); s[5] = (short)f32_to_bf16(v1.y);
    s[6] = (short)f32_to_bf16(v1.z); s[7] = (short)f32_to_bf16(v1.w);
    return s;
}
// direct global->LDS DMA, 16B/lane; LDS dest = uniform base + lane*16
__device__ __forceinline__ void gload_lds16(const unsigned short* g, unsigned short* l) {
    __builtin_amdgcn_global_load_lds(
        (const __attribute__((address_space(1))) unsigned int*)g,
        (__attribute__((address_space(3))) unsigned int*)l,
        16, 0, 0);
}

// ---- fused prep, 150 blocks (R11, proven) ----
// [0,72): img cvt (24 frags/block, 6/wave)
// [72,96): rec cvt + Gram fused (4 captions/block, 1 wave each)
// [96,150): n1sq (64 rows/block, 4 threads/row)
__global__ __launch_bounds__(256) void prep_all(
    const float* __restrict__ images, const float* __restrict__ recipes,
    unsigned short* __restrict__ img_p, unsigned short* __restrict__ rec_p,
    unsigned short* __restrict__ Gp, float* __restrict__ n1sq)
{
    __shared__ unsigned short gt[4 * 48 * 56];
    const int bid = blockIdx.x;
    const int t = threadIdx.x;
    const int wv = t >> 6, l = t & 63;
    const int li = l & 15, q = l >> 4;

    if (bid < 72) {
        const int tile = bid / 3, chunk = bid % 3;
        const float* src = images + (size_t)tile * NCOL * D_N;
        unsigned short* dst = img_p + (size_t)tile * 72 * 512;
        #pragma unroll
        for (int ff = 0; ff < 6; ++ff) {
            int f = chunk * 24 + wv * 6 + ff;
            int rg = f >> 3, ks = f & 7;
            const float* p = src + (rg * 16 + li) * D_N + ks * 32 + q * 8;
            *(uint4*)(dst + (size_t)f * 512 + l * 8) =
                cvt8u(*(const float4*)p, *(const float4*)(p + 4));
        }
    } else if (bid < 96) {
        const int c = (bid - 72) * 4 + wv;
        const float* src = recipes + (size_t)c * W_N * D_N;
        unsigned short* rdst = rec_p + (size_t)c * 24 * 512;
        f32x4 acc[3][3];
        #pragma unroll
        for (int m = 0; m < 3; ++m)
            #pragma unroll
            for (int j = 0; j < 3; ++j) acc[m][j] = (f32x4){0.f, 0.f, 0.f, 0.f};
        #pragma unroll
        for (int ks = 0; ks < 8; ++ks) {
            short8 a[3];
            #pragma unroll
            for (int m = 0; m < 3; ++m) {
                const float* p = src + (m * 16 + li) * D_N + ks * 32 + q * 8;
                a[m] = cvt8s(*(const float4*)p, *(const float4*)(p + 4));
                *(short8*)(rdst + ((size_t)m * 8 + ks) * 512 + l * 8) = a[m];
            }
            #pragma unroll
            for (int m = 0; m < 3; ++m)
                #pragma unroll
                for (int j = 0; j < 3; ++j)
                    acc[m][j] = MFMA16(a[m], a[j], acc[m][j]);
        }
        unsigned short* g = gt + wv * 48 * 56;
        #pragma unroll
        for (int m = 0; m < 3; ++m)
            #pragma unroll
            for (int j = 0; j < 3; ++j)
                #pragma unroll
                for (int r = 0; r < 4; ++r)
                    g[(16 * m + 4 * q + r) * 56 + 16 * j + li] =
                        f32_to_bf16(acc[m][j][r]);
        asm volatile("s_waitcnt lgkmcnt(0)" ::: "memory");
        __builtin_amdgcn_sched_barrier(0);
        unsigned short* dst = Gp + (size_t)c * 3072;
        #pragma unroll
        for (int m = 0; m < 3; ++m)
            #pragma unroll
            for (int ks = 0; ks < 2; ++ks) {
                union { short8 s; uint4 u; } v;
                v.u = make_uint4(0u, 0u, 0u, 0u);
                if (32 * ks + 8 * q < 48)
                    v.s = *(const short8*)(g + (16 * m + li) * 56 + 32 * ks + 8 * q);
                *(short8*)(dst + (m * 2 + ks) * 512 + l * 8) = v.s;
            }
    } else {
        const int row = (bid - 96) * 64 + (t >> 2);
        const int sub = t & 3;
        if (row < I_N * R_N) {
            const float4* p = (const float4*)(images + (size_t)row * D_N + sub * 64);
            float s = 0.f;
            #pragma unroll
            for (int k = 0; k < 16; ++k) { float4 v = p[k]; s += dot4f(v, v); }
            s += __shfl_xor(s, 1);
            s += __shfl_xor(s, 2);
            if (sub == 0) n1sq[row] = s;
        }
    }
}

// ---- main: (caption, 4-image tile), 3 waves, XCD-swizzled;
//      DMA rec staging + both B windows prefetched pre-barrier ----
__global__ __launch_bounds__(192, 4) void xattn_main(
    const unsigned short* __restrict__ img_p, const unsigned short* __restrict__ rec_p,
    const unsigned short* __restrict__ Gp, const int* __restrict__ cap_lens,
    const float* __restrict__ n1sq, float* __restrict__ scores)
{
    // 24.6 KB region: rec frags during phase 1, then reused as e-matrix [144][56]
    __shared__ __align__(16) unsigned short ldsA[24 * 512];
    __shared__ float rs[NCOL];
    unsigned short* awL = ldsA;

    const int t = threadIdx.x;
    const int wv = t >> 6;
    const int l = t & 63;
    const int li = l & 15, q = l >> 4;
    // bijective XCD swizzle: 2304 blocks = 8 XCDs x 288
    const int sbid = ((blockIdx.x & 7) * 288) + (blockIdx.x >> 3);
    const int c = sbid % C_N;
    const int T = sbid / C_N;
    const int L = cap_lens[c];
    const int n0 = wv * 48;

    const unsigned short* pB = img_p + ((size_t)T * 72 + wv * 24) * 512 + l * 8;
    short8 bA[2][3], bB[2][3];

    // ---- issue BOTH B windows (ks 0..3) before the staging barrier ----
    #pragma unroll
    for (int kk = 0; kk < 2; ++kk)
        #pragma unroll
        for (int j = 0; j < 3; ++j) {
            bA[kk][j] = *(const short8*)(pB + (j * 8 + kk) * 512);
            bB[kk][j] = *(const short8*)(pB + (j * 8 + 2 + kk) * 512);
        }

    // ---- stage rec frags to LDS via direct DMA (no VGPR round-trip) ----
    {
        const unsigned short* pA = rec_p + (size_t)c * 24 * 512 + l * 8;
        #pragma unroll
        for (int f0 = 0; f0 < 8; ++f0) {
            int f = wv * 8 + f0;
            gload_lds16(pA + (size_t)f * 512, ldsA + f * 512);
        }
    }
    __syncthreads();

    // ---- Phase 1: raw[w][n] via MFMA; B windows pipelined 2-ks ahead ----
    f32x4 acc[3][3];
    #pragma unroll
    for (int m = 0; m < 3; ++m)
        #pragma unroll
        for (int j = 0; j < 3; ++j) acc[m][j] = (f32x4){0.f, 0.f, 0.f, 0.f};

    // compute ks 0,1 (bA)
    #pragma unroll
    for (int kk = 0; kk < 2; ++kk) {
        short8 a[3];
        #pragma unroll
        for (int m = 0; m < 3; ++m)
            a[m] = *(const short8*)(ldsA + (m * 8 + kk) * 512 + l * 8);
        #pragma unroll
        for (int m = 0; m < 3; ++m)
            #pragma unroll
            for (int j = 0; j < 3; ++j)
                acc[m][j] = MFMA16(a[m], bA[kk][j], acc[m][j]);
    }
    // load ks 4,5 into bA
    #pragma unroll
    for (int kk = 0; kk < 2; ++kk)
        #pragma unroll
        for (int j = 0; j < 3; ++j)
            bA[kk][j] = *(const short8*)(pB + (j * 8 + 4 + kk) * 512);
    // compute ks 2,3 (bB)
    #pragma unroll
    for (int kk = 0; kk < 2; ++kk) {
        short8 a[3];
        #pragma unroll
        for (int m = 0; m < 3; ++m)
            a[m] = *(const short8*)(ldsA + (m * 8 + 2 + kk) * 512 + l * 8);
        #pragma unroll
        for (int m = 0; m < 3; ++m)
            #pragma unroll
            for (int j = 0; j < 3; ++j)
                acc[m][j] = MFMA16(a[m], bB[kk][j], acc[m][j]);
    }
    // load ks 6,7 into bB
    #pragma unroll
    for (int kk = 0; kk < 2; ++kk)
        #pragma unroll
        for (int j = 0; j < 3; ++j)
            bB[kk][j] = *(const short8*)(pB + (j * 8 + 6 + kk) * 512);
    // compute ks 4,5 (bA)
    #pragma unroll
    for (int kk = 0; kk < 2; ++kk) {
        short8 a[3];
        #pragma unroll
        for (int m = 0; m < 3; ++m)
            a[m] = *(const short8*)(ldsA + (m * 8 + 4 + kk) * 512 + l * 8);
        #pragma unroll
        for (int m = 0; m < 3; ++m)
            #pragma unroll
            for (int j = 0; j < 3; ++j)
                acc[m][j] = MFMA16(a[m], bA[kk][j], acc[m][j]);
    }
    // compute ks 6,7 (bB)
    #pragma unroll
    for (int kk = 0; kk < 2; ++kk) {
        short8 a[3];
        #pragma unroll
        for (int m = 0; m < 3; ++m)
            a[m] = *(const short8*)(ldsA + (m * 8 + 6 + kk) * 512 + l * 8);
        #pragma unroll
        for (int m = 0; m < 3; ++m)
            #pragma unroll
            for (int j = 0; j < 3; ++j)
                acc[m][j] = MFMA16(a[m], bB[kk][j], acc[m][j]);
    }
    __syncthreads();   // rec region dead; safe to overwrite with e-matrix

    // ---- early prefetch: Gp frags + n1sq into registers (hidden by softmax) ----
    short8 gA[3][2];
    {
        const unsigned short* pg = Gp + (size_t)c * 3072 + l * 8;
        #pragma unroll
        for (int m = 0; m < 3; ++m)
            #pragma unroll
            for (int ks = 0; ks < 2; ++ks)
                gA[m][ks] = *(const short8*)(pg + (m * 2 + ks) * 512);
    }
    float n1v[3];
    #pragma unroll
    for (int j = 0; j < 3; ++j)
        n1v[j] = n1sq[T * NCOL + n0 + 16 * j + li];

    // ---- Phase 2: leaky/norm/exp with s- and max-cancellation (R8/R9-verified) ----
    float nume[3];
    #pragma unroll
    for (int j = 0; j < 3; ++j) {
        const int n = n0 + 16 * j + li;
        float v[3][4];
        float ssq = 0.f;
        #pragma unroll
        for (int m = 0; m < 3; ++m)
            #pragma unroll
            for (int r = 0; r < 4; ++r) {
                int w = 16 * m + 4 * q + r;
                float x = acc[m][j][r];
                float lv = fmaxf(x, 0.1f * x);          // leaky_relu
                float lm = (w < L) ? lv : 0.f;
                v[m][r] = lm;
                ssq = fmaf(lm, lm, ssq);
            }
        ssq += __shfl_xor(ssq, 16); ssq += __shfl_xor(ssq, 32);
        float inv = LAM_SM * rsqrtf(fmaxf(ssq, 1e-24f));
        float np = 0.f;
        #pragma unroll
        for (int m = 0; m < 3; ++m) {
            int w0 = 16 * m + 4 * q;
            float e0 = (w0     < L) ? __expf(v[m][0] * inv) : 0.f;
            float e1 = (w0 + 1 < L) ? __expf(v[m][1] * inv) : 0.f;
            float e2 = (w0 + 2 < L) ? __expf(v[m][2] * inv) : 0.f;
            float e3 = (w0 + 3 < L) ? __expf(v[m][3] * inv) : 0.f;
            np = fmaf(e0, acc[m][j][0], np);
            np = fmaf(e1, acc[m][j][1], np);
            np = fmaf(e2, acc[m][j][2], np);
            np = fmaf(e3, acc[m][j][3], np);
            unsigned lo, hi;
            asm("v_cvt_pk_bf16_f32 %0, %1, %2" : "=v"(lo) : "v"(e0), "v"(e1));
            asm("v_cvt_pk_bf16_f32 %0, %1, %2" : "=v"(hi) : "v"(e2), "v"(e3));
            *(uint2*)(awL + n * AWS + 16 * m + 4 * q) = make_uint2(lo, hi);
        }
        np += __shfl_xor(np, 16); np += __shfl_xor(np, 32);
        nume[j] = np;
    }
    // e rows [n0, n0+48) are wave-private: wave-lockstep LDS drain, no block barrier
    asm volatile("s_waitcnt lgkmcnt(0)" ::: "memory");
    __builtin_amdgcn_sched_barrier(0);

    // ---- Phase 3: H[w][n] = G . e  (K=48; G zero-padded to 64) ----
    #pragma unroll
    for (int m = 0; m < 3; ++m)
        #pragma unroll
        for (int j = 0; j < 3; ++j) acc[m][j] = (f32x4){0.f, 0.f, 0.f, 0.f};
    #pragma unroll
    for (int ks = 0; ks < 2; ++ks) {
        short8 b[3];
        #pragma unroll
        for (int j = 0; j < 3; ++j) {
            union { short8 s; uint4 u; } bv;
            bv.u = make_uint4(0u, 0u, 0u, 0u);
            if (32 * ks + 8 * q < 48) {
                const uint2* p =
                    (const uint2*)(awL + (n0 + 16 * j + li) * AWS + 32 * ks + 8 * q);
                uint2 x0 = p[0], x1 = p[1];
                bv.u = make_uint4(x0.x, x0.y, x1.x, x1.y);
            }
            b[j] = bv.s;
        }
        #pragma unroll
        for (int m = 0; m < 3; ++m)
            #pragma unroll
            for (int j = 0; j < 3; ++j)
                acc[m][j] = MFMA16(gA[m][ks], b[j], acc[m][j]);
    }

    // ---- Phase 4: n2e = e.H per column; rs = nume * rsqrt(n1*n2e) ----
    #pragma unroll
    for (int j = 0; j < 3; ++j) {
        const int n = n0 + 16 * j + li;
        const unsigned short* ap = awL + n * AWS + 4 * q;
        float n2p = 0.f;
        #pragma unroll
        for (int m = 0; m < 3; ++m) {
            uint2 u = *(const uint2*)(ap + 16 * m);
            n2p = fmaf(__uint_as_float(u.x << 16),          acc[m][j][0], n2p);
            n2p = fmaf(__uint_as_float(u.x & 0xffff0000u),  acc[m][j][1], n2p);
            n2p = fmaf(__uint_as_float(u.y << 16),          acc[m][j][2], n2p);
            n2p = fmaf(__uint_as_float(u.y & 0xffff0000u),  acc[m][j][3], n2p);
        }
        n2p += __shfl_xor(n2p, 16); n2p += __shfl_xor(n2p, 32);
        if (q == 0)
            rs[n] = nume[j] * rsqrtf(fmaxf(n1v[j] * n2p, 1e-16f));
    }
    __syncthreads();

    // ---- Phase 5: LSE over r per image ----
    if (t < 32) {
        int ii = t >> 3, k = t & 7;
        float mx = -1e30f;
        #pragma unroll
        for (int p = 0; p < 5; ++p) {
            int r = k + 8 * p;
            if (r < R_N) mx = fmaxf(mx, rs[ii * R_N + r]);
        }
        mx = fmaxf(mx, __shfl_xor(mx, 1));
        mx = fmaxf(mx, __shfl_xor(mx, 2));
        mx = fmaxf(mx, __shfl_xor(mx, 4));
        float s = 0.f;
        #pragma unroll
        for (int p = 0; p < 5; ++p) {
            int r = k + 8 * p;
            if (r < R_N) s += __expf(LAM_LSE * (rs[ii * R_N + r] - mx));
        }
        s += __shfl_xor(s, 1); s += __shfl_xor(s, 2); s += __shfl_xor(s, 4);
        if (k == 0)
            scores[(size_t)(T * NIMG + ii) * C_N + c] =
                (LAM_LSE * mx + __logf(s)) / LAM_LSE;
    }
}

__global__ __launch_bounds__(256) void hinge_loss_kernel(
    const float* __restrict__ S, float* __restrict__ out)
{
    __shared__ float diag[96];
    __shared__ float wsum[4];
    const int t = threadIdx.x;
    if (t < 96) diag[t] = S[t * 97];
    __syncthreads();
    float acc = 0.f;
    for (int k = t; k < 96 * 96; k += 256) {
        int ii = k / 96;
        int cc = k - ii * 96;
        if (ii != cc) {
            float s = S[k];
            acc += fmaxf(MARGIN_F + s - diag[cc], 0.f)
                 + fmaxf(MARGIN_F + s - diag[ii], 0.f);
        }
    }
    #pragma unroll
    for (int off = 32; off; off >>= 1) acc += __shfl_xor(acc, off);
    if ((t & 63) == 0) wsum[t >> 6] = acc;
    __syncthreads();
    if (t == 0) out[0] = wsum[0] + wsum[1] + wsum[2] + wsum[3];
}

extern "C" void kernel_launch(void* const* d_in, const int* in_sizes, int n_in,
                              void* d_out, int out_size, void* d_ws, size_t ws_size,
                              hipStream_t stream) {
    const float* images  = (const float*)d_in[0];
    const float* recipes = (const float*)d_in[1];
    const int*   caps    = (const int*)d_in[2];
    float* out = (float*)d_out;
    float* wsf = (float*)d_ws;
    float* scores = wsf + WSF_SCORES;
    float* n1 = wsf + WSF_N1;
    unsigned short* shb = (unsigned short*)(wsf + WSF_SHBASE);
    unsigned short* img_p = shb + SH_IMG;
    unsigned short* rec_p = shb + SH_REC;
    unsigned short* Gpp   = shb + SH_GP;

    hipLaunchKernelGGL(prep_all, dim3(150), dim3(256), 0, stream,
                       images, recipes, img_p, rec_p, Gpp, n1);
    hipLaunchKernelGGL(xattn_main, dim3(2304), dim3(192), 0, stream,
                       img_p, rec_p, Gpp, caps, n1, scores);
    hipLaunchKernelGGL(hinge_loss_kernel, dim3(1), dim3(256), 0, stream, scores, out);
}

// Round 13
// 38.871 us; speedup vs baseline: 1.2224x; 1.2224x over previous
//
#include <hip/hip_runtime.h>
#include <math.h>

#define I_N 96
#define C_N 96
#define R_N 36
#define W_N 48
#define D_N 256
#define NIMG 4
#define NCOL (NIMG * R_N)   // 144
#define LAM_SM 9.0f
#define LAM_LSE 6.0f
#define MARGIN_F 0.2f
#define AWS 56              // e-matrix LDS row stride (shorts): 112B

#define IMG_ELEMS (I_N * R_N * D_N)   // 884736 = 24 tiles * 72 frags * 512
#define REC_ELEMS (C_N * W_N * D_N)   // 1179648

// workspace layout
#define WSF_SCORES 0          // 9216 floats
#define WSF_N1     9216       // 3456 floats
#define WSF_SHBASE 12800      // shorts begin here
#define SH_IMG 0
#define SH_REC IMG_ELEMS
#define SH_GP  (IMG_ELEMS + REC_ELEMS)   // 96*6*512 shorts

typedef __attribute__((ext_vector_type(8))) short short8;
typedef __attribute__((ext_vector_type(4))) float f32x4;

#define MFMA16(a, b, c) __builtin_amdgcn_mfma_f32_16x16x32_bf16(a, b, c, 0, 0, 0)

__device__ __forceinline__ unsigned short f32_to_bf16(float f) {
    unsigned int u = __float_as_uint(f);
    return (unsigned short)((u + 0x7fffu + ((u >> 16) & 1u)) >> 16);
}
__device__ __forceinline__ float dot4f(float4 a, float4 b) {
    return a.x * b.x + a.y * b.y + a.z * b.z + a.w * b.w;
}
__device__ __forceinline__ uint4 cvt8u(float4 v0, float4 v1) {
    uint4 o;
    o.x = (unsigned)f32_to_bf16(v0.x) | ((unsigned)f32_to_bf16(v0.y) << 16);
    o.y = (unsigned)f32_to_bf16(v0.z) | ((unsigned)f32_to_bf16(v0.w) << 16);
    o.z = (unsigned)f32_to_bf16(v1.x) | ((unsigned)f32_to_bf16(v1.y) << 16);
    o.w = (unsigned)f32_to_bf16(v1.z) | ((unsigned)f32_to_bf16(v1.w) << 16);
    return o;
}
__device__ __forceinline__ short8 cvt8s(float4 v0, float4 v1) {
    short8 s;
    s[0] = (short)f32_to_bf16(v0.x); s[1] = (short)f32_to_bf16(v0.y);
    s[2] = (short)f32_to_bf16(v0.z); s[3] = (short)f32_to_bf16(v0.w);
    s[4] = (short)f32_to_bf16(v1.x); s[5] = (short)f32_to_bf16(v1.y);
    s[6] = (short)f32_to_bf16(v1.z); s[7] = (short)f32_to_bf16(v1.w);
    return s;
}

// ---- fused prep, 150 blocks (R11, proven) ----
// [0,72): img cvt (24 frags/block, 6/wave)
// [72,96): rec cvt + Gram fused (4 captions/block, 1 wave each)
// [96,150): n1sq (64 rows/block, 4 threads/row)
__global__ __launch_bounds__(256) void prep_all(
    const float* __restrict__ images, const float* __restrict__ recipes,
    unsigned short* __restrict__ img_p, unsigned short* __restrict__ rec_p,
    unsigned short* __restrict__ Gp, float* __restrict__ n1sq)
{
    __shared__ unsigned short gt[4 * 48 * 56];
    const int bid = blockIdx.x;
    const int t = threadIdx.x;
    const int wv = t >> 6, l = t & 63;
    const int li = l & 15, q = l >> 4;

    if (bid < 72) {
        const int tile = bid / 3, chunk = bid % 3;
        const float* src = images + (size_t)tile * NCOL * D_N;
        unsigned short* dst = img_p + (size_t)tile * 72 * 512;
        #pragma unroll
        for (int ff = 0; ff < 6; ++ff) {
            int f = chunk * 24 + wv * 6 + ff;
            int rg = f >> 3, ks = f & 7;
            const float* p = src + (rg * 16 + li) * D_N + ks * 32 + q * 8;
            *(uint4*)(dst + (size_t)f * 512 + l * 8) =
                cvt8u(*(const float4*)p, *(const float4*)(p + 4));
        }
    } else if (bid < 96) {
        const int c = (bid - 72) * 4 + wv;
        const float* src = recipes + (size_t)c * W_N * D_N;
        unsigned short* rdst = rec_p + (size_t)c * 24 * 512;
        f32x4 acc[3][3];
        #pragma unroll
        for (int m = 0; m < 3; ++m)
            #pragma unroll
            for (int j = 0; j < 3; ++j) acc[m][j] = (f32x4){0.f, 0.f, 0.f, 0.f};
        #pragma unroll
        for (int ks = 0; ks < 8; ++ks) {
            short8 a[3];
            #pragma unroll
            for (int m = 0; m < 3; ++m) {
                const float* p = src + (m * 16 + li) * D_N + ks * 32 + q * 8;
                a[m] = cvt8s(*(const float4*)p, *(const float4*)(p + 4));
                *(short8*)(rdst + ((size_t)m * 8 + ks) * 512 + l * 8) = a[m];
            }
            #pragma unroll
            for (int m = 0; m < 3; ++m)
                #pragma unroll
                for (int j = 0; j < 3; ++j)
                    acc[m][j] = MFMA16(a[m], a[j], acc[m][j]);
        }
        unsigned short* g = gt + wv * 48 * 56;
        #pragma unroll
        for (int m = 0; m < 3; ++m)
            #pragma unroll
            for (int j = 0; j < 3; ++j)
                #pragma unroll
                for (int r = 0; r < 4; ++r)
                    g[(16 * m + 4 * q + r) * 56 + 16 * j + li] =
                        f32_to_bf16(acc[m][j][r]);
        asm volatile("s_waitcnt lgkmcnt(0)" ::: "memory");
        __builtin_amdgcn_sched_barrier(0);
        unsigned short* dst = Gp + (size_t)c * 3072;
        #pragma unroll
        for (int m = 0; m < 3; ++m)
            #pragma unroll
            for (int ks = 0; ks < 2; ++ks) {
                union { short8 s; uint4 u; } v;
                v.u = make_uint4(0u, 0u, 0u, 0u);
                if (32 * ks + 8 * q < 48)
                    v.s = *(const short8*)(g + (16 * m + li) * 56 + 32 * ks + 8 * q);
                *(short8*)(dst + (m * 2 + ks) * 512 + l * 8) = v.s;
            }
    } else {
        const int row = (bid - 96) * 64 + (t >> 2);
        const int sub = t & 3;
        if (row < I_N * R_N) {
            const float4* p = (const float4*)(images + (size_t)row * D_N + sub * 64);
            float s = 0.f;
            #pragma unroll
            for (int k = 0; k < 16; ++k) { float4 v = p[k]; s += dot4f(v, v); }
            s += __shfl_xor(s, 1);
            s += __shfl_xor(s, 2);
            if (sub == 0) n1sq[row] = s;
        }
    }
}

// ---- main: (caption, 4-image tile), 3 waves, XCD-swizzled, pipelined B loads
//      (byte-identical to R11, the best-measured variant) ----
__global__ __launch_bounds__(192, 4) void xattn_main(
    const unsigned short* __restrict__ img_p, const unsigned short* __restrict__ rec_p,
    const unsigned short* __restrict__ Gp, const int* __restrict__ cap_lens,
    const float* __restrict__ n1sq, float* __restrict__ scores)
{
    // 24.6 KB region: rec frags during phase 1, then reused as e-matrix [144][56]
    __shared__ __align__(16) unsigned short ldsA[24 * 512];
    __shared__ float rs[NCOL];
    unsigned short* awL = ldsA;

    const int t = threadIdx.x;
    const int wv = t >> 6;
    const int l = t & 63;
    const int li = l & 15, q = l >> 4;
    // bijective XCD swizzle: 2304 blocks = 8 XCDs x 288
    const int sbid = ((blockIdx.x & 7) * 288) + (blockIdx.x >> 3);
    const int c = sbid % C_N;
    const int T = sbid / C_N;
    const int L = cap_lens[c];
    const int n0 = wv * 48;

    const unsigned short* pB = img_p + ((size_t)T * 72 + wv * 24) * 512 + l * 8;
    short8 bA[2][3], bB[2][3];

    // ---- issue first B window BEFORE the staging barrier (overlaps stage latency) ----
    #pragma unroll
    for (int kk = 0; kk < 2; ++kk)
        #pragma unroll
        for (int j = 0; j < 3; ++j)
            bA[kk][j] = *(const short8*)(pB + (j * 8 + kk) * 512);

    // ---- stage rec frags to LDS once per block ----
    {
        const unsigned short* pA = rec_p + (size_t)c * 24 * 512 + l * 8;
        #pragma unroll
        for (int f0 = 0; f0 < 8; ++f0) {
            int f = wv * 8 + f0;
            *(short8*)(ldsA + f * 512 + l * 8) = *(const short8*)(pA + f * 512);
        }
    }
    __syncthreads();

    // ---- Phase 1: raw[w][n] via MFMA; B windows pipelined 2-ks ahead ----
    f32x4 acc[3][3];
    #pragma unroll
    for (int m = 0; m < 3; ++m)
        #pragma unroll
        for (int j = 0; j < 3; ++j) acc[m][j] = (f32x4){0.f, 0.f, 0.f, 0.f};

    // load ks 2,3
    #pragma unroll
    for (int kk = 0; kk < 2; ++kk)
        #pragma unroll
        for (int j = 0; j < 3; ++j)
            bB[kk][j] = *(const short8*)(pB + (j * 8 + 2 + kk) * 512);
    // compute ks 0,1
    #pragma unroll
    for (int kk = 0; kk < 2; ++kk) {
        short8 a[3];
        #pragma unroll
        for (int m = 0; m < 3; ++m)
            a[m] = *(const short8*)(ldsA + (m * 8 + kk) * 512 + l * 8);
        #pragma unroll
        for (int m = 0; m < 3; ++m)
            #pragma unroll
            for (int j = 0; j < 3; ++j)
                acc[m][j] = MFMA16(a[m], bA[kk][j], acc[m][j]);
    }
    // load ks 4,5
    #pragma unroll
    for (int kk = 0; kk < 2; ++kk)
        #pragma unroll
        for (int j = 0; j < 3; ++j)
            bA[kk][j] = *(const short8*)(pB + (j * 8 + 4 + kk) * 512);
    // compute ks 2,3
    #pragma unroll
    for (int kk = 0; kk < 2; ++kk) {
        short8 a[3];
        #pragma unroll
        for (int m = 0; m < 3; ++m)
            a[m] = *(const short8*)(ldsA + (m * 8 + 2 + kk) * 512 + l * 8);
        #pragma unroll
        for (int m = 0; m < 3; ++m)
            #pragma unroll
            for (int j = 0; j < 3; ++j)
                acc[m][j] = MFMA16(a[m], bB[kk][j], acc[m][j]);
    }
    // load ks 6,7
    #pragma unroll
    for (int kk = 0; kk < 2; ++kk)
        #pragma unroll
        for (int j = 0; j < 3; ++j)
            bB[kk][j] = *(const short8*)(pB + (j * 8 + 6 + kk) * 512);
    // compute ks 4,5
    #pragma unroll
    for (int kk = 0; kk < 2; ++kk) {
        short8 a[3];
        #pragma unroll
        for (int m = 0; m < 3; ++m)
            a[m] = *(const short8*)(ldsA + (m * 8 + 4 + kk) * 512 + l * 8);
        #pragma unroll
        for (int m = 0; m < 3; ++m)
            #pragma unroll
            for (int j = 0; j < 3; ++j)
                acc[m][j] = MFMA16(a[m], bA[kk][j], acc[m][j]);
    }
    // compute ks 6,7
    #pragma unroll
    for (int kk = 0; kk < 2; ++kk) {
        short8 a[3];
        #pragma unroll
        for (int m = 0; m < 3; ++m)
            a[m] = *(const short8*)(ldsA + (m * 8 + 6 + kk) * 512 + l * 8);
        #pragma unroll
        for (int m = 0; m < 3; ++m)
            #pragma unroll
            for (int j = 0; j < 3; ++j)
                acc[m][j] = MFMA16(a[m], bB[kk][j], acc[m][j]);
    }
    __syncthreads();   // rec region dead; safe to overwrite with e-matrix

    // ---- early prefetch: Gp frags + n1sq into registers (hidden by softmax) ----
    short8 gA[3][2];
    {
        const unsigned short* pg = Gp + (size_t)c * 3072 + l * 8;
        #pragma unroll
        for (int m = 0; m < 3; ++m)
            #pragma unroll
            for (int ks = 0; ks < 2; ++ks)
                gA[m][ks] = *(const short8*)(pg + (m * 2 + ks) * 512);
    }
    float n1v[3];
    #pragma unroll
    for (int j = 0; j < 3; ++j)
        n1v[j] = n1sq[T * NCOL + n0 + 16 * j + li];

    // ---- Phase 2: leaky/norm/exp with s- and max-cancellation (R8/R9-verified) ----
    float nume[3];
    #pragma unroll
    for (int j = 0; j < 3; ++j) {
        const int n = n0 + 16 * j + li;
        float v[3][4];
        float ssq = 0.f;
        #pragma unroll
        for (int m = 0; m < 3; ++m)
            #pragma unroll
            for (int r = 0; r < 4; ++r) {
                int w = 16 * m + 4 * q + r;
                float x = acc[m][j][r];
                float lv = fmaxf(x, 0.1f * x);          // leaky_relu
                float lm = (w < L) ? lv : 0.f;
                v[m][r] = lm;
                ssq = fmaf(lm, lm, ssq);
            }
        ssq += __shfl_xor(ssq, 16); ssq += __shfl_xor(ssq, 32);
        float inv = LAM_SM * rsqrtf(fmaxf(ssq, 1e-24f));
        float np = 0.f;
        #pragma unroll
        for (int m = 0; m < 3; ++m) {
            int w0 = 16 * m + 4 * q;
            float e0 = (w0     < L) ? __expf(v[m][0] * inv) : 0.f;
            float e1 = (w0 + 1 < L) ? __expf(v[m][1] * inv) : 0.f;
            float e2 = (w0 + 2 < L) ? __expf(v[m][2] * inv) : 0.f;
            float e3 = (w0 + 3 < L) ? __expf(v[m][3] * inv) : 0.f;
            np = fmaf(e0, acc[m][j][0], np);
            np = fmaf(e1, acc[m][j][1], np);
            np = fmaf(e2, acc[m][j][2], np);
            np = fmaf(e3, acc[m][j][3], np);
            unsigned lo, hi;
            asm("v_cvt_pk_bf16_f32 %0, %1, %2" : "=v"(lo) : "v"(e0), "v"(e1));
            asm("v_cvt_pk_bf16_f32 %0, %1, %2" : "=v"(hi) : "v"(e2), "v"(e3));
            *(uint2*)(awL + n * AWS + 16 * m + 4 * q) = make_uint2(lo, hi);
        }
        np += __shfl_xor(np, 16); np += __shfl_xor(np, 32);
        nume[j] = np;
    }
    // e rows [n0, n0+48) are wave-private: wave-lockstep LDS drain, no block barrier
    asm volatile("s_waitcnt lgkmcnt(0)" ::: "memory");
    __builtin_amdgcn_sched_barrier(0);

    // ---- Phase 3: H[w][n] = G . e  (K=48; G zero-padded to 64) ----
    #pragma unroll
    for (int m = 0; m < 3; ++m)
        #pragma unroll
        for (int j = 0; j < 3; ++j) acc[m][j] = (f32x4){0.f, 0.f, 0.f, 0.f};
    #pragma unroll
    for (int ks = 0; ks < 2; ++ks) {
        short8 b[3];
        #pragma unroll
        for (int j = 0; j < 3; ++j) {
            union { short8 s; uint4 u; } bv;
            bv.u = make_uint4(0u, 0u, 0u, 0u);
            if (32 * ks + 8 * q < 48) {
                const uint2* p =
                    (const uint2*)(awL + (n0 + 16 * j + li) * AWS + 32 * ks + 8 * q);
                uint2 x0 = p[0], x1 = p[1];
                bv.u = make_uint4(x0.x, x0.y, x1.x, x1.y);
            }
            b[j] = bv.s;
        }
        #pragma unroll
        for (int m = 0; m < 3; ++m)
            #pragma unroll
            for (int j = 0; j < 3; ++j)
                acc[m][j] = MFMA16(gA[m][ks], b[j], acc[m][j]);
    }

    // ---- Phase 4: n2e = e.H per column; rs = nume * rsqrt(n1*n2e) ----
    #pragma unroll
    for (int j = 0; j < 3; ++j) {
        const int n = n0 + 16 * j + li;
        const unsigned short* ap = awL + n * AWS + 4 * q;
        float n2p = 0.f;
        #pragma unroll
        for (int m = 0; m < 3; ++m) {
            uint2 u = *(const uint2*)(ap + 16 * m);
            n2p = fmaf(__uint_as_float(u.x << 16),          acc[m][j][0], n2p);
            n2p = fmaf(__uint_as_float(u.x & 0xffff0000u),  acc[m][j][1], n2p);
            n2p = fmaf(__uint_as_float(u.y << 16),          acc[m][j][2], n2p);
            n2p = fmaf(__uint_as_float(u.y & 0xffff0000u),  acc[m][j][3], n2p);
        }
        n2p += __shfl_xor(n2p, 16); n2p += __shfl_xor(n2p, 32);
        if (q == 0)
            rs[n] = nume[j] * rsqrtf(fmaxf(n1v[j] * n2p, 1e-16f));
    }
    __syncthreads();

    // ---- Phase 5: LSE over r per image ----
    if (t < 32) {
        int ii = t >> 3, k = t & 7;
        float mx = -1e30f;
        #pragma unroll
        for (int p = 0; p < 5; ++p) {
            int r = k + 8 * p;
            if (r < R_N) mx = fmaxf(mx, rs[ii * R_N + r]);
        }
        mx = fmaxf(mx, __shfl_xor(mx, 1));
        mx = fmaxf(mx, __shfl_xor(mx, 2));
        mx = fmaxf(mx, __shfl_xor(mx, 4));
        float s = 0.f;
        #pragma unroll
        for (int p = 0; p < 5; ++p) {
            int r = k + 8 * p;
            if (r < R_N) s += __expf(LAM_LSE * (rs[ii * R_N + r] - mx));
        }
        s += __shfl_xor(s, 1); s += __shfl_xor(s, 2); s += __shfl_xor(s, 4);
        if (k == 0)
            scores[(size_t)(T * NIMG + ii) * C_N + c] =
                (LAM_LSE * mx + __logf(s)) / LAM_LSE;
    }
}

// ---- hinge: 1024 threads (16 waves), 9 entries/thread, deterministic LDS tree ----
__global__ __launch_bounds__(1024) void hinge_loss_kernel(
    const float* __restrict__ S, float* __restrict__ out)
{
    __shared__ float diag[96];
    __shared__ float wsum[16];
    const int t = threadIdx.x;
    if (t < 96) diag[t] = S[t * 97];
    __syncthreads();
    float acc = 0.f;
    #pragma unroll
    for (int p = 0; p < 9; ++p) {
        int k = t + 1024 * p;
        if (k < C_N * C_N) {
            int ii = k / 96;
            int cc = k - ii * 96;
            if (ii != cc) {
                float s = S[k];
                acc += fmaxf(MARGIN_F + s - diag[cc], 0.f)
                     + fmaxf(MARGIN_F + s - diag[ii], 0.f);
            }
        }
    }
    #pragma unroll
    for (int off = 32; off; off >>= 1) acc += __shfl_xor(acc, off);
    if ((t & 63) == 0) wsum[t >> 6] = acc;
    __syncthreads();
    if (t == 0) {
        float s = 0.f;
        #pragma unroll
        for (int w = 0; w < 16; ++w) s += wsum[w];
        out[0] = s;
    }
}

extern "C" void kernel_launch(void* const* d_in, const int* in_sizes, int n_in,
                              void* d_out, int out_size, void* d_ws, size_t ws_size,
                              hipStream_t stream) {
    const float* images  = (const float*)d_in[0];
    const float* recipes = (const float*)d_in[1];
    const int*   caps    = (const int*)d_in[2];
    float* out = (float*)d_out;
    float* wsf = (float*)d_ws;
    float* scores = wsf + WSF_SCORES;
    float* n1 = wsf + WSF_N1;
    unsigned short* shb = (unsigned short*)(wsf + WSF_SHBASE);
    unsigned short* img_p = shb + SH_IMG;
    unsigned short* rec_p = shb + SH_REC;
    unsigned short* Gpp   = shb + SH_GP;

    hipLaunchKernelGGL(prep_all, dim3(150), dim3(256), 0, stream,
                       images, recipes, img_p, rec_p, Gpp, n1);
    hipLaunchKernelGGL(xattn_main, dim3(2304), dim3(192), 0, stream,
                       img_p, rec_p, Gpp, caps, n1, scores);
    hipLaunchKernelGGL(hinge_loss_kernel, dim3(1), dim3(1024), 0, stream, scores, out);
}